// Round 1
// baseline (210.626 us; speedup 1.0000x reference)
//
#include <hip/hip_runtime.h>

namespace {
constexpr int   S_GRID   = 14;
constexpr int   CH       = 30;
constexpr float L_COORD  = 5.0f;
constexpr float L_NOOBJ  = 0.5f;
constexpr float BOX_EPS  = 1e-20f;
constexpr int   BLOCK    = 256;   // threads per block
constexpr int   TILE     = 256;   // cells per block (== BLOCK: 1 cell/thread)
}

// One block stages TILE cells (TILE*30 floats per tensor) from global to LDS
// with fully-coalesced float4 loads, then each thread computes the complete
// per-cell YOLO loss from LDS and the block reduces to one atomicAdd.
// LDS: 2 * 256*30*4 = 61440 B -> 2 blocks/CU (8 waves/CU), LDS-limited.
__global__ __launch_bounds__(BLOCK) void yolo_loss_kernel(
    const float* __restrict__ pred,
    const float* __restrict__ tgt,
    float* __restrict__ out,
    float inv_n)
{
    __shared__ float sp[TILE * CH];
    __shared__ float st[TILE * CH];
    __shared__ float wsum[BLOCK / 64];

    const int tid = threadIdx.x;
    const size_t base = (size_t)blockIdx.x * (TILE * CH);

    // ---- stage global -> LDS, coalesced float4 (block base is 30720B-aligned)
    const float4* gp4 = reinterpret_cast<const float4*>(pred + base);
    const float4* gt4 = reinterpret_cast<const float4*>(tgt + base);
    float4* sp4 = reinterpret_cast<float4*>(sp);
    float4* st4 = reinterpret_cast<float4*>(st);
    constexpr int NV4 = TILE * CH / 4;  // 1920
    #pragma unroll
    for (int i = 0; i < (NV4 + BLOCK - 1) / BLOCK; ++i) {
        int idx = tid + i * BLOCK;
        if (idx < NV4) {
            sp4[idx] = gp4[idx];
            st4[idx] = gt4[idx];
        }
    }
    __syncthreads();

    // ---- per-cell compute (thread tid owns cell tid of the tile)
    // tid*30 floats = 120 B offset -> 8B aligned, float2 LDS reads are legal.
    const float* p = sp + tid * CH;
    const float* t = st + tid * CH;
    float pv[CH], tv[CH];
    #pragma unroll
    for (int j = 0; j < CH / 2; ++j) {
        float2 a = reinterpret_cast<const float2*>(p)[j];
        pv[2 * j] = a.x; pv[2 * j + 1] = a.y;
        float2 b = reinterpret_cast<const float2*>(t)[j];
        tv[2 * j] = b.x; tv[2 * j + 1] = b.y;
    }

    const float objf   = ((tv[4] + tv[9]) > 0.0f) ? 1.0f : 0.0f;
    const float noobjf = 1.0f - objf;

    // no-object confidence loss
    const float d4 = pv[4] - tv[4];
    const float d9 = pv[9] - tv[9];
    const float no_obj = noobjf * (d4 * d4 + d9 * d9);

    // class loss (channels 10..29)
    float cls = 0.0f;
    #pragma unroll
    for (int j = 10; j < CH; ++j) {
        const float d = pv[j] - tv[j];
        cls += d * d;
    }
    cls *= objf;

    // per-box IoU (elementwise "diagonal" IoU), corner form as in reference
    float iou[2];
    constexpr float invS = 1.0f / (float)S_GRID;
    #pragma unroll
    for (int b = 0; b < 2; ++b) {
        const float* bp = pv + 5 * b;
        const float* bt = tv + 5 * b;
        const float txc = bt[0] * invS, tyc = bt[1] * invS;
        const float tx1 = txc - 0.5f * bt[2], tx2 = txc + 0.5f * bt[2];
        const float ty1 = tyc - 0.5f * bt[3], ty2 = tyc + 0.5f * bt[3];
        const float pxc = bp[0] * invS, pyc = bp[1] * invS;
        const float px1 = pxc - 0.5f * bp[2], px2 = pxc + 0.5f * bp[2];
        const float py1 = pyc - 0.5f * bp[3], py2 = pyc + 0.5f * bp[3];
        const float iw = fmaxf(fminf(tx2, px2) - fmaxf(tx1, px1), 0.0f);
        const float ih = fmaxf(fminf(ty2, py2) - fmaxf(ty1, py1), 0.0f);
        const float inter  = iw * ih;
        const float area_t = (tx2 - tx1) * (ty2 - ty1);
        const float area_p = (px2 - px1) * (py2 - py1);
        iou[b] = inter / (area_t + area_p - inter);
    }

    // responsible-box selection: a0 = iou0 > iou1 ; a1 = float(a0) <= iou1
    const bool  a0   = iou[0] > iou[1];
    const bool  a1   = (a0 ? 1.0f : 0.0f) <= iou[1];
    const float sel0 = a0 ? 1.0f : 0.0f;
    const float sel1 = a1 ? 1.0f : 0.0f;

    float contain = 0.0f, regr = 0.0f;
    #pragma unroll
    for (int b = 0; b < 2; ++b) {
        const float w  = objf * (b == 0 ? sel0 : sel1);
        const float* bp = pv + 5 * b;
        const float* bt = tv + 5 * b;
        const float dc = bp[4] - iou[b];
        contain += w * dc * dc;
        const float dx  = bp[0] - bt[0];
        const float dy  = bp[1] - bt[1];
        const float dsw = sqrtf(bp[2] + BOX_EPS) - sqrtf(bt[2] + BOX_EPS);
        const float dsh = sqrtf(bp[3] + BOX_EPS) - sqrtf(bt[3] + BOX_EPS);
        regr += w * (dx * dx + dy * dy + dsw * dsw + dsh * dsh);
    }

    float acc = L_COORD * regr + contain + L_NOOBJ * no_obj + cls;

    // ---- block reduction: wave shuffle, then cross-wave via LDS
    #pragma unroll
    for (int off = 32; off > 0; off >>= 1)
        acc += __shfl_down(acc, off, 64);
    const int lane = tid & 63;
    const int wid  = tid >> 6;
    if (lane == 0) wsum[wid] = acc;
    __syncthreads();
    if (tid == 0) {
        const float s = (wsum[0] + wsum[1]) + (wsum[2] + wsum[3]);
        atomicAdd(out, s * inv_n);
    }
}

extern "C" void kernel_launch(void* const* d_in, const int* in_sizes, int n_in,
                              void* d_out, int out_size, void* d_ws, size_t ws_size,
                              hipStream_t stream) {
    const float* pred = (const float*)d_in[0];
    const float* tgt  = (const float*)d_in[1];
    float* out = (float*)d_out;

    const int ncells = in_sizes[0] / CH;              // 4096*14*14 = 802816
    const int n_batch = ncells / (S_GRID * S_GRID);   // 4096
    const int grid = ncells / TILE;                   // 3136 (exact)

    // harness re-poisons d_out to 0xAA before every timed launch
    hipMemsetAsync(out, 0, sizeof(float), stream);
    yolo_loss_kernel<<<grid, BLOCK, 0, stream>>>(pred, tgt, out,
                                                 1.0f / (float)n_batch);
}